// Round 1
// baseline (12884.447 us; speedup 1.0000x reference)
//
#include <hip/hip_runtime.h>

typedef __attribute__((ext_vector_type(8))) short short8;
typedef __attribute__((ext_vector_type(4))) float f32x4;
typedef unsigned short u16;
typedef unsigned int u32;

#define T_LEN 512
#define BATCH 64
#define HID 400
#define GATES 1200   // 3*HID
#define DIN 800      // layer input width (D == 2H)
#define KTOT 1200    // DIN + HID
#define WSTRIDE 1216 // K padded to 38*32
#define HSTRIDE 416  // HID padded to 13*32

__device__ __forceinline__ u16 f2bf(float f) {
    u32 u = __builtin_bit_cast(u32, f);
    u += 0x7fffu + ((u >> 16) & 1u);
    return (u16)(u >> 16);
}
__device__ __forceinline__ float sigmoidf_(float x) { return 1.f / (1.f + expf(-x)); }

// ---------------- cast kernels ----------------
__global__ void cast_f32_bf16(const float* __restrict__ in, u16* __restrict__ out, int n) {
    for (int i = blockIdx.x * blockDim.x + threadIdx.x; i < n; i += gridDim.x * blockDim.x)
        out[i] = f2bf(in[i]);
}

// W_bf layout: [2][GATES][WSTRIDE], cols >= 1200 zeroed
__global__ void cast_W(const float* __restrict__ fW, const float* __restrict__ bW,
                       u16* __restrict__ W_bf, int layer) {
    const int n = 2 * GATES * WSTRIDE;
    for (int i = blockIdx.x * blockDim.x + threadIdx.x; i < n; i += gridDim.x * blockDim.x) {
        int d = i / (GATES * WSTRIDE);
        int rem = i - d * (GATES * WSTRIDE);
        int r = rem / WSTRIDE;
        int k = rem - r * WSTRIDE;
        const float* src = (d ? bW : fW) + (size_t)layer * GATES * KTOT;
        W_bf[i] = (k < KTOT) ? f2bf(src[(size_t)r * KTOT + k]) : (u16)0;
    }
}

// h_bf: [2][BATCH][HSTRIDE] (pad zeroed), c_ws: [2][BATCH][HID]
__global__ void init_states(const float* __restrict__ f_init, const float* __restrict__ b_init,
                            u16* __restrict__ h_bf, float* __restrict__ c_ws, int layer) {
    const int n = 2 * BATCH * HSTRIDE;
    for (int i = blockIdx.x * blockDim.x + threadIdx.x; i < n; i += gridDim.x * blockDim.x) {
        int d = i / (BATCH * HSTRIDE);
        int rem = i - d * (BATCH * HSTRIDE);
        int b = rem / HSTRIDE;
        int k = rem - b * HSTRIDE;
        const float* src = (d ? b_init : f_init) + layer * 2 * HID;
        h_bf[i] = (k < HID) ? f2bf(src[k]) : (u16)0;
        if (k < HID) c_ws[d * (BATCH * HID) + b * HID + k] = src[HID + k];
    }
}

// ---------------- LSTM step (both directions) ----------------
// grid: (25 h-col blocks of 16, 4 batch blocks of 16, 2 dirs), block: 192 (3 waves = gates i,j,o)
__global__ __launch_bounds__(192) void lstm_step(
    const u16* __restrict__ x_bf,   // [T*B, DIN]
    const u16* __restrict__ W_bf,   // [2][GATES][WSTRIDE]
    const float* __restrict__ fb_l, // [GATES]
    const float* __restrict__ bb_l, // [GATES]
    const float* __restrict__ masks,// [T*B]
    u16* __restrict__ h_bf,         // [2][B][HSTRIDE]
    float* __restrict__ c_ws,       // [2][B][HID]
    float* __restrict__ raw,        // [T*B, 2H]
    int t_fw)
{
    const int dir = blockIdx.z;
    const int t = dir ? (T_LEN - 1 - t_fw) : t_fw;
    const int pl = blockIdx.x;            // h-col block
    const int bb = blockIdx.y * 16;       // batch base
    const int tid = threadIdx.x;
    const int lane = tid & 63;
    const int gate = tid >> 6;            // 0:i 1:j 2:o
    const int l15 = lane & 15, hi = lane >> 4;

    const int prow = gate * HID + pl * 16 + l15;  // row in W
    const float bval = (dir ? bb_l : fb_l)[prow];
    f32x4 acc = {bval, bval, bval, bval};

    const u16* Arow = x_bf + ((size_t)(t * BATCH + bb + l15)) * DIN + 8 * hi;
    const u16* Brow = W_bf + (size_t)dir * GATES * WSTRIDE + (size_t)prow * WSTRIDE + 8 * hi;
    const u16* Hrow = h_bf + dir * (BATCH * HSTRIDE) + (bb + l15) * HSTRIDE + 8 * hi;

#pragma unroll
    for (int kk = 0; kk < 25; ++kk) {   // x part: k = 0..800
        short8 a = *(const short8*)(Arow + kk * 32);
        short8 b = *(const short8*)(Brow + kk * 32);
        acc = __builtin_amdgcn_mfma_f32_16x16x32_bf16(a, b, acc, 0, 0, 0);
    }
#pragma unroll
    for (int kk = 0; kk < 13; ++kk) {   // h part: k = 800..1216 (padded)
        short8 a = *(const short8*)(Hrow + kk * 32);
        short8 b = *(const short8*)(Brow + (25 + kk) * 32);
        acc = __builtin_amdgcn_mfma_f32_16x16x32_bf16(a, b, acc, 0, 0, 0);
    }

    __shared__ float gsm[3][16][16];
#pragma unroll
    for (int j = 0; j < 4; ++j) gsm[gate][hi * 4 + j][l15] = acc[j];
    __syncthreads();

    for (int idx = tid; idx < 256; idx += 192) {
        int bi = idx >> 4, c = idx & 15;
        int bg = bb + bi;
        int col = pl * 16 + c;
        float ig = sigmoidf_(gsm[0][bi][c]);
        float jg = tanhf(gsm[1][bi][c]);
        float og = sigmoidf_(gsm[2][bi][c]);
        float m = masks[t * BATCH + bg];
        float* cp = c_ws + dir * (BATCH * HID) + bg * HID + col;
        float cold = *cp;
        float cnew = m * ((1.f - ig) * cold + ig * jg);
        float hnew = m * (tanhf(cnew) * og);
        *cp = cnew;
        h_bf[dir * (BATCH * HSTRIDE) + bg * HSTRIDE + col] = f2bf(hnew);
        raw[((size_t)t * BATCH + bg) * (2 * HID) + dir * HID + col] = hnew;
    }
}

// ---------------- save final h/c states ----------------
__global__ void save_states(const float* __restrict__ raw, const float* __restrict__ c_ws,
                            float* __restrict__ out, int layer) {
    const int n = 2 * BATCH * HID;
    for (int i = blockIdx.x * blockDim.x + threadIdx.x; i < n; i += gridDim.x * blockDim.x) {
        int d = i / (BATCH * HID);
        int rem = i - d * (BATCH * HID);
        int b = rem / HID;
        int k = rem - b * HID;
        int t = d ? 0 : (T_LEN - 1);
        float h = raw[((size_t)t * BATCH + b) * (2 * HID) + d * HID + k];
        size_t base = (size_t)T_LEN * BATCH * (2 * HID);
        size_t idx = ((size_t)(2 * layer + d) * BATCH + b) * HID + k;
        out[base + idx] = h;
        out[base + (size_t)2 * 3 * BATCH * HID + idx] = c_ws[d * (BATCH * HID) + b * HID + k];
    }
}

// ---------------- highway: gates GEMM + fused sigmoid blend ----------------
// gp = sigmoid(rawout @ pW^T + pb); Rcur = gp*Rcur + (1-gp)*Iprev  (in place)
// A (bf16 cast of Rcur raw) [32768, 800], Bw [800, 800]
__global__ __launch_bounds__(256) void highway_gemm(
    const u16* __restrict__ A, const u16* __restrict__ Bw, const float* __restrict__ pb,
    float* __restrict__ Rcur, const float* __restrict__ Iprev)
{
    const int m0 = blockIdx.x * 128;
    const int n0 = blockIdx.y * 128;
    const int tid = threadIdx.x, lane = tid & 63, wave = tid >> 6;
    const int wy = wave >> 1, wx = wave & 1;
    const int l15 = lane & 15, hi = lane >> 4;
    const short8 zero8 = {};

    f32x4 acc[4][4] = {};
    const int arow0 = m0 + wy * 64 + l15;
    const int brow0 = n0 + wx * 64 + l15;

    for (int kk = 0; kk < 25; ++kk) {
        const int k0 = kk * 32 + 8 * hi;
        short8 a[4], b[4];
#pragma unroll
        for (int mf = 0; mf < 4; ++mf)
            a[mf] = *(const short8*)(A + (size_t)(arow0 + mf * 16) * DIN + k0);
#pragma unroll
        for (int nf = 0; nf < 4; ++nf) {
            int br = brow0 + nf * 16;
            b[nf] = (br < DIN) ? *(const short8*)(Bw + (size_t)br * DIN + k0) : zero8;
        }
#pragma unroll
        for (int mf = 0; mf < 4; ++mf)
#pragma unroll
            for (int nf = 0; nf < 4; ++nf)
                acc[mf][nf] = __builtin_amdgcn_mfma_f32_16x16x32_bf16(a[mf], b[nf], acc[mf][nf], 0, 0, 0);
    }

#pragma unroll
    for (int mf = 0; mf < 4; ++mf)
#pragma unroll
        for (int nf = 0; nf < 4; ++nf)
#pragma unroll
            for (int j = 0; j < 4; ++j) {
                int row = m0 + wy * 64 + mf * 16 + hi * 4 + j;
                int col = n0 + wx * 64 + nf * 16 + l15;
                if (col < DIN) {
                    float g = sigmoidf_(acc[mf][nf][j] + pb[col]);
                    size_t off = (size_t)row * DIN + col;
                    Rcur[off] = g * Rcur[off] + (1.f - g) * Iprev[off];
                }
            }
}

// ---------------- host ----------------
extern "C" void kernel_launch(void* const* d_in, const int* in_sizes, int n_in,
                              void* d_out, int out_size, void* d_ws, size_t ws_size,
                              hipStream_t stream) {
    const float* x      = (const float*)d_in[0];
    const float* masks  = (const float*)d_in[1];
    const float* fW     = (const float*)d_in[2];
    const float* fb     = (const float*)d_in[3];
    const float* bW     = (const float*)d_in[4];
    const float* bb     = (const float*)d_in[5];
    const float* f_init = (const float*)d_in[6];
    const float* b_init = (const float*)d_in[7];
    const float* pW     = (const float*)d_in[8];
    const float* pb     = (const float*)d_in[9];
    float* out = (float*)d_out;

    char* ws = (char*)d_ws;
    // layout (bytes):
    float* R0   = (float*)(ws + 0);                       // 104,857,600
    float* R1   = (float*)(ws + 104857600);               // 104,857,600
    u16* x_bf   = (u16*)(ws + 209715200);                 //  52,428,800
    u16* W_bf   = (u16*)(ws + 262144000);                 //   5,836,800
    u16* pW_bf  = (u16*)(ws + 267980800);                 //   1,280,000
    u16* h_bf   = (u16*)(ws + 269260800);                 //     106,496
    float* c_ws = (float*)(ws + 269367296);               //     204,800
    const int N_TB = T_LEN * BATCH * DIN;                 // 26,214,400 elems

    for (int layer = 0; layer < 3; ++layer) {
        float* raw = (layer == 0) ? R0 : (layer == 1) ? R1 : out;
        const float* inp_f32 = (layer == 0) ? x : (layer == 1) ? R0 : R1;

        cast_f32_bf16<<<4096, 256, 0, stream>>>(inp_f32, x_bf, N_TB);
        cast_W<<<4096, 256, 0, stream>>>(fW, bW, W_bf, layer);
        init_states<<<(2 * BATCH * HSTRIDE + 255) / 256, 256, 0, stream>>>(f_init, b_init, h_bf, c_ws, layer);

        for (int t = 0; t < T_LEN; ++t)
            lstm_step<<<dim3(25, 4, 2), 192, 0, stream>>>(
                x_bf, W_bf, fb + layer * GATES, bb + layer * GATES, masks, h_bf, c_ws, raw, t);

        save_states<<<200, 256, 0, stream>>>(raw, c_ws, out, layer);

        if (layer > 0) {
            // bf16-cast the RAW bidirectional output (pre-highway) for the gate GEMM
            cast_f32_bf16<<<4096, 256, 0, stream>>>(raw, x_bf, N_TB);
            cast_f32_bf16<<<2048, 256, 0, stream>>>(pW + (size_t)(layer - 1) * DIN * DIN, pW_bf, DIN * DIN);
            highway_gemm<<<dim3(256, 7), 256, 0, stream>>>(
                x_bf, pW_bf, pb + (layer - 1) * DIN, raw, inp_f32);
        }
    }
}